// Round 7
// baseline (457.042 us; speedup 1.0000x reference)
//
#include <hip/hip_runtime.h>

// Convolution_1228360646680 — equivariant graph conv, MFMA + LDS-staged gather
// N=25000, E=400000, MUL=32, NSC=8, HID=64
//
// Pipeline:
//   prep:      scaled W1s (8x64 f32), W2T (128x64 f32, fallback), W2Tb (128x64 bf16)
//   node_in:   xsv1[n][128] = a[n]/sqrt(32) * (x @ w1)
//   CSR:       count -> scan -> scatter (permutes esrc/eattr into dst-sorted order)
//   edge_mlp_mfma: per sorted 16-edge tile; h in regs (A-frag layout), W2 bf16
//              B-frags register-resident; 16 MFMA; C-frags stored raw -> wbuf
//   gather_out: grid-stride block per node; per 16-edge chunk stage 16 xsv1 rows
//              (8KB) + eattr into LDS with wide coalesced loads, inner loop is
//              LDS-only + streaming wbuf; then fused w2 transform -> out directly
//   fallback:  atomic scatter-add + node_out if ws too small

typedef __attribute__((ext_vector_type(8))) short bf16x8;
typedef __attribute__((ext_vector_type(4))) float f32x4;

__device__ __forceinline__ unsigned bf16r(float x) {
    unsigned u = __float_as_uint(x);
    return (u + 0x7fffu + ((u >> 16) & 1u)) >> 16;   // RNE
}
__device__ __forceinline__ float bf16tof(unsigned short v) {
    return __uint_as_float(((unsigned)v) << 16);
}

__global__ __launch_bounds__(256) void prep_kernel(
    const float* __restrict__ Wfc1, const float* __restrict__ Wfc2,
    float* __restrict__ W1s, float* __restrict__ W2T, unsigned short* __restrict__ W2Tb)
{
    int t = blockIdx.x * 256 + threadIdx.x;
    const float inv_sqrt_nsc = 0.35355339059327373f; // 1/sqrt(8)
    if (t < 8 * 64) W1s[t] = Wfc1[t] * inv_sqrt_nsc;
    if (t < 64 * 128) {
        int r = t >> 7, c = t & 127;
        float v = Wfc2[t] * 0.125f;                  // 1/sqrt(64)
        W2T[c * 64 + r] = v;
        W2Tb[c * 64 + r] = (unsigned short)bf16r(v);
    }
}

__global__ __launch_bounds__(256) void node_in_kernel(
    const float* __restrict__ node_input, const float* __restrict__ attr_in,
    const float* __restrict__ w1s, const float* __restrict__ w1v,
    float* __restrict__ xsv1, int n_nodes)
{
    __shared__ float sWs[1024], sWv[1024], srow[2][128];
    for (int k = threadIdx.x; k < 1024; k += 256) { sWs[k] = w1s[k]; sWv[k] = w1v[k]; }
    int j = threadIdx.x & 127;
    int half = threadIdx.x >> 7;
    int w = 0, i = 0;
    if (j >= 32) { int jj = j - 32; w = jj / 3; i = jj - 3 * w; }
    const float inv1 = 0.17677669529663687f; // 1/sqrt(32)
    for (int base = blockIdx.x * 2; base < n_nodes; base += gridDim.x * 2) {
        int n = base + half;
        __syncthreads();
        if (n < n_nodes) srow[half][j] = node_input[(size_t)n * 128 + j];
        __syncthreads();
        if (n < n_nodes) {
            float acc = 0.0f;
            if (j < 32) {
                #pragma unroll
                for (int u = 0; u < 32; u++) acc += srow[half][u] * sWs[u * 32 + j];
            } else {
                #pragma unroll
                for (int u = 0; u < 32; u++) acc += srow[half][32 + 3 * u + i] * sWv[u * 32 + w];
            }
            xsv1[(size_t)n * 128 + j] = acc * (attr_in[n] * inv1);
        }
    }
}

// ---------------- CSR build ----------------
__global__ __launch_bounds__(256) void count_kernel(
    const int* __restrict__ edst, int* __restrict__ counts, int n_edges)
{
    int e = blockIdx.x * 256 + threadIdx.x;
    if (e < n_edges) atomicAdd(&counts[edst[e]], 1);
}

__global__ __launch_bounds__(1024) void scan_kernel(
    const int* __restrict__ counts, int* __restrict__ offs, int* __restrict__ cursor, int n)
{
    __shared__ int part[1024];
    int tid = threadIdx.x;
    int chunk = (n + 1023) / 1024;
    int begin = tid * chunk;
    int end = begin + chunk; if (end > n) end = n;
    int s = 0;
    for (int i = begin; i < end; i++) s += counts[i];
    part[tid] = s;
    __syncthreads();
    for (int off = 1; off < 1024; off <<= 1) {
        int v = (tid >= off) ? part[tid - off] : 0;
        __syncthreads();
        part[tid] += v;
        __syncthreads();
    }
    int base = (tid == 0) ? 0 : part[tid - 1];
    for (int i = begin; i < end; i++) {
        offs[i] = base; cursor[i] = base;
        base += counts[i];
    }
    if (tid == 1023) offs[n] = part[1023];
}

__global__ __launch_bounds__(256) void scatter_kernel(
    const int* __restrict__ edst, const int* __restrict__ esrc,
    const float* __restrict__ eattr,
    int* __restrict__ cursor, int* __restrict__ elist,
    int* __restrict__ esrc_s, float4* __restrict__ eattr_s, int n_edges)
{
    int e = blockIdx.x * 256 + threadIdx.x;
    if (e < n_edges) {
        int p = atomicAdd(&cursor[edst[e]], 1);
        elist[p] = e;
        esrc_s[p] = esrc[e];
        eattr_s[p] = *reinterpret_cast<const float4*>(eattr + (size_t)e * 4);
    }
}

// ---------------- edge MLP via MFMA (sorted order) ----------------
// wbuf layout: per 16x16 tile (rt = k>>4, ct = col>>4), 256 bf16 in C-fragment
// order: elem = lane*4 + reg, lane = ((m>>2)<<4)|n, reg = m&3  (m=k&15, n=col&15)
__global__ __launch_bounds__(256) void edge_mlp_mfma(
    const float* __restrict__ escal, const int* __restrict__ elist,
    const float* __restrict__ W1s, const unsigned short* __restrict__ W2Tb,
    unsigned short* __restrict__ wbuf, int n_edges, int nrt)
{
    int tid = threadIdx.x;
    int w = tid >> 6, l = tid & 63;
    int lm = l & 15, lk = l >> 4;            // edge-in-tile / k-group
    int rt = blockIdx.x * 4 + w;             // sorted-position 16-edge row tile
    int kidx = rt * 16 + lm;                 // sorted position
    int k0 = lk * 8;

    // B fragments: 8 col-tiles x 2 K-halves, register resident (64 VGPR)
    bf16x8 bf[8][2];
    #pragma unroll
    for (int t = 0; t < 8; t++) {
        int n = t * 16 + lm;
        bf[t][0] = *reinterpret_cast<const bf16x8*>(W2Tb + n * 64 + k0);
        bf[t][1] = *reinterpret_cast<const bf16x8*>(W2Tb + n * 64 + k0 + 32);
    }

    // escal row for this lane's edge (gathered via elist)
    float q[8];
    if (kidx < n_edges) {
        int e = elist[kidx];
        float4 qa = *reinterpret_cast<const float4*>(escal + (size_t)e * 8);
        float4 qb = *reinterpret_cast<const float4*>(escal + (size_t)e * 8 + 4);
        q[0] = qa.x; q[1] = qa.y; q[2] = qa.z; q[3] = qa.w;
        q[4] = qb.x; q[5] = qb.y; q[6] = qb.z; q[7] = qb.w;
    } else {
        #pragma unroll
        for (int i = 0; i < 8; i++) q[i] = 0.f;
    }

    // h = silu(q @ W1s) for k0..k0+7 and k0+32..k0+39 -> two A fragments
    union Af { bf16x8 v; unsigned u[4]; };
    Af af0, af1;
    #pragma unroll
    for (int half = 0; half < 2; half++) {
        int kb = k0 + half * 32;
        float h[8];
        #pragma unroll
        for (int i = 0; i < 8; i++) h[i] = 0.f;
        #pragma unroll
        for (int in = 0; in < 8; in++) {
            float qi = q[in];
            float4 wa = *reinterpret_cast<const float4*>(W1s + in * 64 + kb);
            float4 wb = *reinterpret_cast<const float4*>(W1s + in * 64 + kb + 4);
            h[0] += qi * wa.x; h[1] += qi * wa.y; h[2] += qi * wa.z; h[3] += qi * wa.w;
            h[4] += qi * wb.x; h[5] += qi * wb.y; h[6] += qi * wb.z; h[7] += qi * wb.w;
        }
        unsigned* dst = half ? af1.u : af0.u;
        #pragma unroll
        for (int p = 0; p < 4; p++) {
            float s0 = h[2 * p], s1 = h[2 * p + 1];
            s0 = s0 / (1.0f + __expf(-s0));
            s1 = s1 / (1.0f + __expf(-s1));
            dst[p] = bf16r(s0) | (bf16r(s1) << 16);
        }
    }

    // MFMA: 8 col-tiles x (K=64 as 2x32)
    f32x4 acc[8];
    #pragma unroll
    for (int t = 0; t < 8; t++) { acc[t][0] = 0.f; acc[t][1] = 0.f; acc[t][2] = 0.f; acc[t][3] = 0.f; }
    #pragma unroll
    for (int t = 0; t < 8; t++) {
        acc[t] = __builtin_amdgcn_mfma_f32_16x16x32_bf16(af0.v, bf[t][0], acc[t], 0, 0, 0);
        acc[t] = __builtin_amdgcn_mfma_f32_16x16x32_bf16(af1.v, bf[t][1], acc[t], 0, 0, 0);
    }

    // store C fragments raw: per tile, lane stores 4 bf16 (8B) at lane*8
    if (rt < nrt) {
        #pragma unroll
        for (int t = 0; t < 8; t++) {
            unsigned s0 = bf16r(acc[t][0]) | (bf16r(acc[t][1]) << 16);
            unsigned s1 = bf16r(acc[t][2]) | (bf16r(acc[t][3]) << 16);
            *reinterpret_cast<uint2*>(wbuf + ((size_t)(rt * 8 + t) * 256) + l * 4) = make_uint2(s0, s1);
        }
    }
}

// ---------------- fused gather + node_out: LDS-staged rows, LDS-only inner loop ----------------
__global__ __launch_bounds__(256) void gather_out_kernel(
    const unsigned short* __restrict__ wbuf, const float* __restrict__ xsv1,
    const int* __restrict__ esrc_s, const float4* __restrict__ eattr_s,
    const int* __restrict__ offs, const float* __restrict__ attr_out,
    const float* __restrict__ w2s, const float* __restrict__ w2v,
    float* __restrict__ out, int n_nodes)
{
    __shared__ float sW[4096];                 // w2s (2048) then w2v (2048)
    __shared__ float rows[16][128];            // 16 staged xsv1 rows
    __shared__ float4 eas[16];
    __shared__ float smid[256];

    int tid = threadIdx.x;
    for (int idx = tid; idx < 2048; idx += 256) { sW[idx] = w2s[idx]; sW[2048 + idx] = w2v[idx]; }

    int kind, u = 0, i = 0, col;
    if (tid < 32)       { kind = 0; u = tid;       col = tid; }
    else if (tid < 64)  { kind = 1; u = tid - 32;  col = 96 + u; }
    else if (tid < 160) { int q = tid - 64;  u = q / 3; i = q - 3 * u; kind = 2; col = 32 + u; }
    else                { int q = tid - 160; u = q / 3; i = q - 3 * u; kind = 3; col = 64 + u; }
    const int colpart = ((col >> 4) << 8) + ((col & 15) << 2);
    const float inv_sqrt3 = 0.5773502691896258f;

    // transform-role decode (threads 0..127 produce out features)
    int tw = 0, ti = 0;
    if (tid >= 32 && tid < 128) { int jj = tid - 32; tw = jj / 3; ti = jj - 3 * tw; }

    __syncthreads();   // sW ready

    for (int n = blockIdx.x; n < n_nodes; n += gridDim.x) {
        int start = offs[n], end = offs[n + 1];
        float acc = 0.0f;

        for (int k0 = start; k0 < end; k0 += 16) {
            int cmax = end - k0; if (cmax > 16) cmax = 16;
            // stage: 32 threads per row, float4 each -> 512B coalesced per row
            for (int idx = tid; idx < (cmax << 5); idx += 256) {
                int r = idx >> 5, qq = idx & 31;
                int src = esrc_s[k0 + r];
                *reinterpret_cast<float4*>(&rows[r][qq * 4]) =
                    *reinterpret_cast<const float4*>(xsv1 + (size_t)src * 128 + qq * 4);
            }
            if (tid < cmax) eas[tid] = eattr_s[k0 + tid];
            __syncthreads();

            for (int c = 0; c < cmax; c++) {
                int k = k0 + c;
                int ep = ((k >> 4) << 11) + (((k >> 2) & 3) << 6) + (k & 3);
                float wvv = bf16tof(wbuf[ep + colpart]);
                float4 ea = eas[c];
                const float* __restrict__ nb = rows[c];
                if (kind == 0)      acc += wvv * nb[u] * ea.x;
                else if (kind == 1) acc += wvv * (nb[32 + 3 * u] * ea.y + nb[33 + 3 * u] * ea.z
                                                  + nb[34 + 3 * u] * ea.w) * inv_sqrt3;
                else if (kind == 2) { float yvi = (i == 0) ? ea.y : (i == 1) ? ea.z : ea.w;
                                      acc += wvv * nb[u] * yvi; }
                else                acc += wvv * ea.x * nb[32 + 3 * u + i];
            }
            __syncthreads();   // rows consumed, safe to restage
        }

        smid[tid] = acc;
        __syncthreads();

        if (tid < 128) {
            float o = 0.0f;
            if (tid < 32) {
                #pragma unroll
                for (int uu = 0; uu < 32; uu++)
                    o += smid[uu] * sW[uu * 32 + tid] + smid[32 + uu] * sW[1024 + uu * 32 + tid];
            } else {
                #pragma unroll
                for (int uu = 0; uu < 32; uu++)
                    o += smid[64 + 3 * uu + ti] * sW[2048 + uu * 32 + tw]
                       + smid[160 + 3 * uu + ti] * sW[3072 + uu * 32 + tw];
            }
            out[(size_t)n * 128 + tid] = o * (attr_out[n] * 0.03125f); // 1/sqrt(64)/sqrt(16)
        }
        __syncthreads();   // smid consumed before next node overwrites
    }
}

// ---------------- fallback atomic edge kernel (ws too small) ----------------
__global__ __launch_bounds__(256) void edge_kernel_atomic(
    const float* __restrict__ xsv1, const int* __restrict__ esrc, const int* __restrict__ edst,
    const float* __restrict__ eattr, const float* __restrict__ escal,
    const float* __restrict__ W1s, const float* __restrict__ W2T,
    float* __restrict__ mid, int n_edges)
{
    int e = blockIdx.x * 256 + threadIdx.x;
    if (e >= n_edges) return;
    const float4 qa = *reinterpret_cast<const float4*>(escal + (size_t)e * 8);
    const float4 qb = *reinterpret_cast<const float4*>(escal + (size_t)e * 8 + 4);
    float h[64];
    #pragma unroll
    for (int t = 0; t < 64; t++) {
        float acc = qa.x * W1s[t]       + qa.y * W1s[64 + t]
                  + qa.z * W1s[128 + t] + qa.w * W1s[192 + t]
                  + qb.x * W1s[256 + t] + qb.y * W1s[320 + t]
                  + qb.z * W1s[384 + t] + qb.w * W1s[448 + t];
        h[t] = acc / (1.0f + __expf(-acc));
    }
    int src = esrc[e], dst = edst[e];
    const float4 ea = *reinterpret_cast<const float4*>(eattr + (size_t)e * 4);
    const float ys = ea.x, yv0 = ea.y, yv1 = ea.z, yv2 = ea.w;
    const float* __restrict__ nb = xsv1 + (size_t)src * 128;
    float* __restrict__ op = mid + (size_t)dst * 256;
    const float inv_sqrt3 = 0.5773502691896258f;
    for (int u = 0; u < 32; u++) {
        float w0 = 0.f, w1 = 0.f, w2 = 0.f, w3 = 0.f;
        const float* __restrict__ r0 = W2T + (size_t)u * 64;
        const float* __restrict__ r1 = W2T + (size_t)(32 + u) * 64;
        const float* __restrict__ r2 = W2T + (size_t)(64 + u) * 64;
        const float* __restrict__ r3 = W2T + (size_t)(96 + u) * 64;
        #pragma unroll
        for (int t = 0; t < 64; t++) {
            float hv = h[t];
            w0 += hv * r0[t]; w1 += hv * r1[t]; w2 += hv * r2[t]; w3 += hv * r3[t];
        }
        float es  = nb[u];
        float ev0 = nb[32 + 3 * u], ev1 = nb[33 + 3 * u], ev2 = nb[34 + 3 * u];
        atomicAdd(op + u,      w0 * es * ys);
        atomicAdd(op + 32 + u, w3 * (ev0 * yv0 + ev1 * yv1 + ev2 * yv2) * inv_sqrt3);
        float a1 = w1 * es;
        atomicAdd(op + 64 + 3 * u, a1 * yv0);
        atomicAdd(op + 65 + 3 * u, a1 * yv1);
        atomicAdd(op + 66 + 3 * u, a1 * yv2);
        float a2 = w2 * ys;
        atomicAdd(op + 160 + 3 * u, a2 * ev0);
        atomicAdd(op + 161 + 3 * u, a2 * ev1);
        atomicAdd(op + 162 + 3 * u, a2 * ev2);
    }
}

__global__ __launch_bounds__(256) void node_out_kernel(
    const float* __restrict__ mid, const float* __restrict__ attr_out,
    const float* __restrict__ w2s, const float* __restrict__ w2v,
    float* __restrict__ out, int n_nodes)
{
    __shared__ float sS0[1024], sS1[1024], sV0[1024], sV1[1024];
    for (int k = threadIdx.x; k < 1024; k += 256) {
        sS0[k] = w2s[k]; sS1[k] = w2s[1024 + k];
        sV0[k] = w2v[k]; sV1[k] = w2v[1024 + k];
    }
    __syncthreads();
    int j = threadIdx.x & 127;
    int half = threadIdx.x >> 7;
    int w = 0, i = 0;
    if (j >= 32) { int jj = j - 32; w = jj / 3; i = jj - 3 * w; }
    const float scale = 0.125f * 0.25f;
    for (int base = blockIdx.x * 2; base < n_nodes; base += gridDim.x * 2) {
        int n = base + half;
        if (n >= n_nodes) continue;
        const float* __restrict__ mr = mid + (size_t)n * 256;
        float acc = 0.0f;
        if (j < 32) {
            #pragma unroll
            for (int u = 0; u < 32; u++)
                acc += mr[u] * sS0[u * 32 + j] + mr[32 + u] * sS1[u * 32 + j];
        } else {
            #pragma unroll
            for (int u = 0; u < 32; u++)
                acc += mr[64 + 3 * u + i] * sV0[u * 32 + w] + mr[160 + 3 * u + i] * sV1[u * 32 + w];
        }
        out[(size_t)n * 128 + j] = acc * (attr_out[n] * scale);
    }
}

extern "C" void kernel_launch(void* const* d_in, const int* in_sizes, int n_in,
                              void* d_out, int out_size, void* d_ws, size_t ws_size,
                              hipStream_t stream)
{
    const float* node_input = (const float*)d_in[0];
    const float* attr_in    = (const float*)d_in[1];
    const float* attr_out   = (const float*)d_in[2];
    const int*   esrc       = (const int*)d_in[3];
    const int*   edst       = (const int*)d_in[4];
    const float* eattr      = (const float*)d_in[5];
    const float* escal      = (const float*)d_in[6];
    const float* w1s        = (const float*)d_in[7];
    const float* w1v        = (const float*)d_in[8];
    const float* Wfc1       = (const float*)d_in[9];
    const float* Wfc2       = (const float*)d_in[10];
    const float* w2s        = (const float*)d_in[11];
    const float* w2v        = (const float*)d_in[12];
    float* out = (float*)d_out;

    int n_nodes = in_sizes[0] / 128;
    int n_edges = in_sizes[3];
    int nrt = (n_edges + 15) / 16;

    // workspace layout (aligned)
    char* p = (char*)d_ws;
    auto alloc = [&](size_t bytes, size_t align) -> void* {
        size_t a = (size_t)p; a = (a + align - 1) & ~(align - 1);
        p = (char*)a; void* r = (void*)p; p += bytes; return r;
    };
    float* xsv1 = (float*)alloc((size_t)n_nodes * 128 * 4, 16);
    float* W1s  = (float*)alloc(512 * 4, 16);
    float* W2T  = (float*)alloc(8192 * 4, 16);
    float* mid  = (float*)alloc((size_t)n_nodes * 256 * 4, 16);
    int* counts = (int*)alloc((size_t)n_nodes * 4, 16);
    int* offs   = (int*)alloc(((size_t)n_nodes + 1) * 4, 16);
    int* cursor = (int*)alloc((size_t)n_nodes * 4, 16);
    int* elist  = (int*)alloc((size_t)n_edges * 4, 16);
    int* esrc_s = (int*)alloc((size_t)n_edges * 4, 16);
    float4* eattr_s = (float4*)alloc((size_t)n_edges * 16, 16);
    unsigned short* W2Tb = (unsigned short*)alloc(8192 * 2, 64);
    unsigned short* wbuf = (unsigned short*)alloc((size_t)nrt * 8 * 256 * 2, 64);
    size_t needed = (size_t)(p - (char*)d_ws);

    prep_kernel<<<32, 256, 0, stream>>>(Wfc1, Wfc2, W1s, W2T, W2Tb);
    node_in_kernel<<<2048, 256, 0, stream>>>(node_input, attr_in, w1s, w1v, xsv1, n_nodes);

    if (ws_size >= needed) {
        hipMemsetAsync(counts, 0, (size_t)n_nodes * sizeof(int), stream);
        count_kernel<<<(n_edges + 255) / 256, 256, 0, stream>>>(edst, counts, n_edges);
        scan_kernel<<<1, 1024, 0, stream>>>(counts, offs, cursor, n_nodes);
        scatter_kernel<<<(n_edges + 255) / 256, 256, 0, stream>>>(
            edst, esrc, eattr, cursor, elist, esrc_s, eattr_s, n_edges);
        edge_mlp_mfma<<<(n_edges + 63) / 64, 256, 0, stream>>>(
            escal, elist, W1s, W2Tb, wbuf, n_edges, nrt);
        gather_out_kernel<<<2048, 256, 0, stream>>>(
            wbuf, xsv1, esrc_s, eattr_s, offs, attr_out, w2s, w2v, out, n_nodes);
    } else {
        hipMemsetAsync(mid, 0, (size_t)n_nodes * 256 * sizeof(float), stream);
        edge_kernel_atomic<<<(n_edges + 255) / 256, 256, 0, stream>>>(
            xsv1, esrc, edst, eattr, escal, W1s, W2T, mid, n_edges);
        node_out_kernel<<<2048, 256, 0, stream>>>(mid, attr_out, w2s, w2v, out, n_nodes);
    }
}

// Round 8
// 419.334 us; speedup vs baseline: 1.0899x; 1.0899x over previous
//
#include <hip/hip_runtime.h>

// Convolution_1228360646680 — equivariant graph conv, fully fused producer/consumer
// N=25000, E=400000, MUL=32, NSC=8, HID=64
//
// Pipeline (fast path):
//   prep:     scaled W1s (8x64 f32), W2T (128x64 f32, fallback only), W2Tb (128x64 bf16)
//   node_in:  xsv1[n][128] = a[n]/sqrt(32) * (x @ w1)
//   CSR:      count -> scan -> scatter (permutes esrc/eattr/escal into dst-sorted order)
//   fused:    block per node; per 16-edge chunk:
//               A: 256 threads compute h=silu(q@W1s) -> LDS (bank-padded)
//               B: each wave 4 MFMAs (its 2 col-tiles) -> 4KB LDS w-tile (validated bijection)
//               C: consumer reads w-col into regs (4x ds_read_b64), round-6 inner loop
//             then fused node_out tail (smid in LDS, w2 read direct from global)
//   fallback: atomic scatter-add + node_out if ws too small

typedef __attribute__((ext_vector_type(8))) short bf16x8;
typedef __attribute__((ext_vector_type(4))) float f32x4;

__device__ __forceinline__ unsigned bf16r(float x) {
    unsigned u = __float_as_uint(x);
    return (u + 0x7fffu + ((u >> 16) & 1u)) >> 16;   // RNE
}
__device__ __forceinline__ float bf16tof(unsigned short v) {
    return __uint_as_float(((unsigned)v) << 16);
}

__global__ __launch_bounds__(256) void prep_kernel(
    const float* __restrict__ Wfc1, const float* __restrict__ Wfc2,
    float* __restrict__ W1s, float* __restrict__ W2T, unsigned short* __restrict__ W2Tb)
{
    int t = blockIdx.x * 256 + threadIdx.x;
    const float inv_sqrt_nsc = 0.35355339059327373f; // 1/sqrt(8)
    if (t < 8 * 64) W1s[t] = Wfc1[t] * inv_sqrt_nsc;
    if (t < 64 * 128) {
        int r = t >> 7, c = t & 127;
        float v = Wfc2[t] * 0.125f;                  // 1/sqrt(64)
        W2T[c * 64 + r] = v;
        W2Tb[c * 64 + r] = (unsigned short)bf16r(v);
    }
}

__global__ __launch_bounds__(256) void node_in_kernel(
    const float* __restrict__ node_input, const float* __restrict__ attr_in,
    const float* __restrict__ w1s, const float* __restrict__ w1v,
    float* __restrict__ xsv1, int n_nodes)
{
    __shared__ float sWs[1024], sWv[1024], srow[2][128];
    for (int k = threadIdx.x; k < 1024; k += 256) { sWs[k] = w1s[k]; sWv[k] = w1v[k]; }
    int j = threadIdx.x & 127;
    int half = threadIdx.x >> 7;
    int w = 0, i = 0;
    if (j >= 32) { int jj = j - 32; w = jj / 3; i = jj - 3 * w; }
    const float inv1 = 0.17677669529663687f; // 1/sqrt(32)
    for (int base = blockIdx.x * 2; base < n_nodes; base += gridDim.x * 2) {
        int n = base + half;
        __syncthreads();
        if (n < n_nodes) srow[half][j] = node_input[(size_t)n * 128 + j];
        __syncthreads();
        if (n < n_nodes) {
            float acc = 0.0f;
            if (j < 32) {
                #pragma unroll
                for (int u = 0; u < 32; u++) acc += srow[half][u] * sWs[u * 32 + j];
            } else {
                #pragma unroll
                for (int u = 0; u < 32; u++) acc += srow[half][32 + 3 * u + i] * sWv[u * 32 + w];
            }
            xsv1[(size_t)n * 128 + j] = acc * (attr_in[n] * inv1);
        }
    }
}

// ---------------- CSR build ----------------
__global__ __launch_bounds__(256) void count_kernel(
    const int* __restrict__ edst, int* __restrict__ counts, int n_edges)
{
    int e = blockIdx.x * 256 + threadIdx.x;
    if (e < n_edges) atomicAdd(&counts[edst[e]], 1);
}

__global__ __launch_bounds__(1024) void scan_kernel(
    const int* __restrict__ counts, int* __restrict__ offs, int* __restrict__ cursor, int n)
{
    __shared__ int part[1024];
    int tid = threadIdx.x;
    int chunk = (n + 1023) / 1024;
    int begin = tid * chunk;
    int end = begin + chunk; if (end > n) end = n;
    int s = 0;
    for (int i = begin; i < end; i++) s += counts[i];
    part[tid] = s;
    __syncthreads();
    for (int off = 1; off < 1024; off <<= 1) {
        int v = (tid >= off) ? part[tid - off] : 0;
        __syncthreads();
        part[tid] += v;
        __syncthreads();
    }
    int base = (tid == 0) ? 0 : part[tid - 1];
    for (int i = begin; i < end; i++) {
        offs[i] = base; cursor[i] = base;
        base += counts[i];
    }
    if (tid == 1023) offs[n] = part[1023];
}

// scatter: permute esrc/eattr/escal into dst-sorted order
__global__ __launch_bounds__(256) void scatter_kernel(
    const int* __restrict__ edst, const int* __restrict__ esrc,
    const float* __restrict__ eattr, const float* __restrict__ escal,
    int* __restrict__ cursor,
    int* __restrict__ esrc_s, float4* __restrict__ eattr_s, float4* __restrict__ escal_s,
    int n_edges)
{
    int e = blockIdx.x * 256 + threadIdx.x;
    if (e < n_edges) {
        int p = atomicAdd(&cursor[edst[e]], 1);
        esrc_s[p] = esrc[e];
        eattr_s[p] = *reinterpret_cast<const float4*>(eattr + (size_t)e * 4);
        escal_s[2 * (size_t)p]     = *reinterpret_cast<const float4*>(escal + (size_t)e * 8);
        escal_s[2 * (size_t)p + 1] = *reinterpret_cast<const float4*>(escal + (size_t)e * 8 + 4);
    }
}

// ---------------- fused: MLP(MFMA) + gather + node_out, all in one block/node ----------------
__global__ __launch_bounds__(256) void fused_kernel(
    const float4* __restrict__ escal_s, const float* __restrict__ W1s_g,
    const unsigned short* __restrict__ W2Tb,
    const float* __restrict__ xsv1, const int* __restrict__ esrc_s,
    const float4* __restrict__ eattr_s, const int* __restrict__ offs,
    const float* __restrict__ attr_out,
    const float* __restrict__ w2s, const float* __restrict__ w2v,
    float* __restrict__ out, int n_nodes)
{
    __shared__ unsigned short h_lds[16][72];   // bf16 h-tile, 144B rows (pad 8 -> bank-clean)
    __shared__ unsigned short w_lds[8 * 256];  // 4KB w-tile, validated tile bijection
    __shared__ float smid[256];

    int tid = threadIdx.x;
    int wv_ = tid >> 6, l = tid & 63;
    int lm = l & 15, lk = l >> 4;

    // B-fragments: this wave's two col-tiles (2w, 2w+1), register-resident
    bf16x8 bfr[2][2];
    #pragma unroll
    for (int tt = 0; tt < 2; tt++) {
        int t = 2 * wv_ + tt;
        int nn = t * 16 + lm;
        bfr[tt][0] = *reinterpret_cast<const bf16x8*>(W2Tb + nn * 64 + lk * 8);
        bfr[tt][1] = *reinterpret_cast<const bf16x8*>(W2Tb + nn * 64 + lk * 8 + 32);
    }

    // consumer feature decode (validated mapping)
    int kind, u = 0, i = 0, col;
    if (tid < 32)       { kind = 0; u = tid;       col = tid; }
    else if (tid < 64)  { kind = 1; u = tid - 32;  col = 96 + u; }
    else if (tid < 160) { int q = tid - 64;  u = q / 3; i = q - 3 * u; kind = 2; col = 32 + u; }
    else                { int q = tid - 160; u = q / 3; i = q - 3 * u; kind = 3; col = 64 + u; }
    const int wbase = ((col >> 4) << 8) + ((col & 15) << 2);   // bf16 units in w_lds
    const float inv_sqrt3 = 0.5773502691896258f;

    // phase-A decode
    int eA = tid & 15, kq = tid >> 4;

    // tail decode
    int twl = 0, til = 0;
    if (tid >= 32 && tid < 128) { int jj = tid - 32; twl = jj / 3; til = jj - 3 * twl; }

    int n = blockIdx.x;
    if (n >= n_nodes) return;            // uniform per block
    int start = offs[n], end = offs[n + 1];
    float acc = 0.0f;

    for (int k0 = start; k0 < end; k0 += 16) {
        int cmax = end - k0; if (cmax > 16) cmax = 16;

        // ---- phase A: h[e][k] = silu(q[e] @ W1s[:,k]), thread (eA, kq) does 4 k's
        {
            float q[8];
            if (eA < cmax) {
                float4 qa = escal_s[2 * (size_t)(k0 + eA)];
                float4 qb = escal_s[2 * (size_t)(k0 + eA) + 1];
                q[0] = qa.x; q[1] = qa.y; q[2] = qa.z; q[3] = qa.w;
                q[4] = qb.x; q[5] = qb.y; q[6] = qb.z; q[7] = qb.w;
            } else {
                #pragma unroll
                for (int z = 0; z < 8; z++) q[z] = 0.0f;
            }
            float h0 = 0.f, h1 = 0.f, h2 = 0.f, h3 = 0.f;
            #pragma unroll
            for (int in_ = 0; in_ < 8; in_++) {
                float4 wr4 = *reinterpret_cast<const float4*>(W1s_g + in_ * 64 + kq * 4);
                h0 += q[in_] * wr4.x; h1 += q[in_] * wr4.y;
                h2 += q[in_] * wr4.z; h3 += q[in_] * wr4.w;
            }
            h0 = h0 / (1.0f + __expf(-h0));
            h1 = h1 / (1.0f + __expf(-h1));
            h2 = h2 / (1.0f + __expf(-h2));
            h3 = h3 / (1.0f + __expf(-h3));
            unsigned d0 = bf16r(h0) | (bf16r(h1) << 16);
            unsigned d1 = bf16r(h2) | (bf16r(h3) << 16);
            *reinterpret_cast<uint2*>(reinterpret_cast<char*>(&h_lds[0][0]) + eA * 144 + kq * 8)
                = make_uint2(d0, d1);
        }
        __syncthreads();

        // ---- phase B: 4 MFMAs per wave, write C-frags to w_lds (tile bijection)
        {
            const char* hb = reinterpret_cast<const char*>(&h_lds[0][0]);
            bf16x8 af0 = *reinterpret_cast<const bf16x8*>(hb + lm * 144 + lk * 16);
            bf16x8 af1 = *reinterpret_cast<const bf16x8*>(hb + lm * 144 + 64 + lk * 16);
            #pragma unroll
            for (int tt = 0; tt < 2; tt++) {
                f32x4 a4 = {0.f, 0.f, 0.f, 0.f};
                a4 = __builtin_amdgcn_mfma_f32_16x16x32_bf16(af0, bfr[tt][0], a4, 0, 0, 0);
                a4 = __builtin_amdgcn_mfma_f32_16x16x32_bf16(af1, bfr[tt][1], a4, 0, 0, 0);
                unsigned s0 = bf16r(a4[0]) | (bf16r(a4[1]) << 16);
                unsigned s1 = bf16r(a4[2]) | (bf16r(a4[3]) << 16);
                *reinterpret_cast<uint2*>(&w_lds[(2 * wv_ + tt) * 256 + l * 4]) = make_uint2(s0, s1);
            }
        }
        __syncthreads();

        // ---- consumer: per-thread w-col into regs, then round-6 inner loop
        {
            unsigned wr[8];
            #pragma unroll
            for (int g = 0; g < 4; g++) {
                uint2 v = *reinterpret_cast<const uint2*>(&w_lds[wbase + g * 64]);
                wr[2 * g] = v.x; wr[2 * g + 1] = v.y;
            }
            #pragma unroll
            for (int c = 0; c < 16; c++) {
                if (c < cmax) {
                    int k = k0 + c;
                    unsigned d = wr[c >> 1];
                    float wvv = (c & 1) ? __uint_as_float(d & 0xffff0000u)
                                        : __uint_as_float(d << 16);
                    int src = esrc_s[k];
                    float4 ea = eattr_s[k];
                    const float* __restrict__ nb = xsv1 + (size_t)src * 128;
                    if (kind == 0)      acc += wvv * nb[u] * ea.x;
                    else if (kind == 1) acc += wvv * (nb[32 + 3 * u] * ea.y + nb[33 + 3 * u] * ea.z
                                                      + nb[34 + 3 * u] * ea.w) * inv_sqrt3;
                    else if (kind == 2) { float yvi = (i == 0) ? ea.y : (i == 1) ? ea.z : ea.w;
                                          acc += wvv * nb[u] * yvi; }
                    else                acc += wvv * ea.x * nb[32 + 3 * u + i];
                }
            }
        }
        // next phase A only touches h_lds (not read by consumer); post-A barrier
        // protects w_lds from phase-B overwrite before all consumers finish.
    }

    // ---- fused node_out tail
    smid[tid] = acc;
    __syncthreads();
    if (tid < 128) {
        float o = 0.0f;
        if (tid < 32) {
            #pragma unroll
            for (int uu = 0; uu < 32; uu++)
                o += smid[uu] * w2s[uu * 32 + tid] + smid[32 + uu] * w2s[1024 + uu * 32 + tid];
        } else {
            #pragma unroll
            for (int uu = 0; uu < 32; uu++)
                o += smid[64 + 3 * uu + til] * w2v[uu * 32 + twl]
                   + smid[160 + 3 * uu + til] * w2v[1024 + uu * 32 + twl];
        }
        out[(size_t)n * 128 + tid] = o * (attr_out[n] * 0.03125f); // 1/sqrt(64)/sqrt(16)
    }
}

// ---------------- fallback atomic edge kernel (ws too small) ----------------
__global__ __launch_bounds__(256) void edge_kernel_atomic(
    const float* __restrict__ xsv1, const int* __restrict__ esrc, const int* __restrict__ edst,
    const float* __restrict__ eattr, const float* __restrict__ escal,
    const float* __restrict__ W1s, const float* __restrict__ W2T,
    float* __restrict__ mid, int n_edges)
{
    int e = blockIdx.x * 256 + threadIdx.x;
    if (e >= n_edges) return;
    const float4 qa = *reinterpret_cast<const float4*>(escal + (size_t)e * 8);
    const float4 qb = *reinterpret_cast<const float4*>(escal + (size_t)e * 8 + 4);
    float h[64];
    #pragma unroll
    for (int t = 0; t < 64; t++) {
        float acc = qa.x * W1s[t]       + qa.y * W1s[64 + t]
                  + qa.z * W1s[128 + t] + qa.w * W1s[192 + t]
                  + qb.x * W1s[256 + t] + qb.y * W1s[320 + t]
                  + qb.z * W1s[384 + t] + qb.w * W1s[448 + t];
        h[t] = acc / (1.0f + __expf(-acc));
    }
    int src = esrc[e], dst = edst[e];
    const float4 ea = *reinterpret_cast<const float4*>(eattr + (size_t)e * 4);
    const float ys = ea.x, yv0 = ea.y, yv1 = ea.z, yv2 = ea.w;
    const float* __restrict__ nb = xsv1 + (size_t)src * 128;
    float* __restrict__ op = mid + (size_t)dst * 256;
    const float inv_sqrt3 = 0.5773502691896258f;
    for (int u = 0; u < 32; u++) {
        float w0 = 0.f, w1 = 0.f, w2 = 0.f, w3 = 0.f;
        const float* __restrict__ r0 = W2T + (size_t)u * 64;
        const float* __restrict__ r1 = W2T + (size_t)(32 + u) * 64;
        const float* __restrict__ r2 = W2T + (size_t)(64 + u) * 64;
        const float* __restrict__ r3 = W2T + (size_t)(96 + u) * 64;
        #pragma unroll
        for (int t = 0; t < 64; t++) {
            float hv = h[t];
            w0 += hv * r0[t]; w1 += hv * r1[t]; w2 += hv * r2[t]; w3 += hv * r3[t];
        }
        float es  = nb[u];
        float ev0 = nb[32 + 3 * u], ev1 = nb[33 + 3 * u], ev2 = nb[34 + 3 * u];
        atomicAdd(op + u,      w0 * es * ys);
        atomicAdd(op + 32 + u, w3 * (ev0 * yv0 + ev1 * yv1 + ev2 * yv2) * inv_sqrt3);
        float a1 = w1 * es;
        atomicAdd(op + 64 + 3 * u, a1 * yv0);
        atomicAdd(op + 65 + 3 * u, a1 * yv1);
        atomicAdd(op + 66 + 3 * u, a1 * yv2);
        float a2 = w2 * ys;
        atomicAdd(op + 160 + 3 * u, a2 * ev0);
        atomicAdd(op + 161 + 3 * u, a2 * ev1);
        atomicAdd(op + 162 + 3 * u, a2 * ev2);
    }
}

__global__ __launch_bounds__(256) void node_out_kernel(
    const float* __restrict__ mid, const float* __restrict__ attr_out,
    const float* __restrict__ w2s, const float* __restrict__ w2v,
    float* __restrict__ out, int n_nodes)
{
    __shared__ float sS0[1024], sS1[1024], sV0[1024], sV1[1024];
    for (int k = threadIdx.x; k < 1024; k += 256) {
        sS0[k] = w2s[k]; sS1[k] = w2s[1024 + k];
        sV0[k] = w2v[k]; sV1[k] = w2v[1024 + k];
    }
    __syncthreads();
    int j = threadIdx.x & 127;
    int half = threadIdx.x >> 7;
    int w = 0, i = 0;
    if (j >= 32) { int jj = j - 32; w = jj / 3; i = jj - 3 * w; }
    const float scale = 0.125f * 0.25f;
    for (int base = blockIdx.x * 2; base < n_nodes; base += gridDim.x * 2) {
        int n = base + half;
        if (n >= n_nodes) continue;
        const float* __restrict__ mr = mid + (size_t)n * 256;
        float acc = 0.0f;
        if (j < 32) {
            #pragma unroll
            for (int u = 0; u < 32; u++)
                acc += mr[u] * sS0[u * 32 + j] + mr[32 + u] * sS1[u * 32 + j];
        } else {
            #pragma unroll
            for (int u = 0; u < 32; u++)
                acc += mr[64 + 3 * u + i] * sV0[u * 32 + w] + mr[160 + 3 * u + i] * sV1[u * 32 + w];
        }
        out[(size_t)n * 128 + j] = acc * (attr_out[n] * scale);
    }
}

extern "C" void kernel_launch(void* const* d_in, const int* in_sizes, int n_in,
                              void* d_out, int out_size, void* d_ws, size_t ws_size,
                              hipStream_t stream)
{
    const float* node_input = (const float*)d_in[0];
    const float* attr_in    = (const float*)d_in[1];
    const float* attr_out   = (const float*)d_in[2];
    const int*   esrc       = (const int*)d_in[3];
    const int*   edst       = (const int*)d_in[4];
    const float* eattr      = (const float*)d_in[5];
    const float* escal      = (const float*)d_in[6];
    const float* w1s        = (const float*)d_in[7];
    const float* w1v        = (const float*)d_in[8];
    const float* Wfc1       = (const float*)d_in[9];
    const float* Wfc2       = (const float*)d_in[10];
    const float* w2s        = (const float*)d_in[11];
    const float* w2v        = (const float*)d_in[12];
    float* out = (float*)d_out;

    int n_nodes = in_sizes[0] / 128;
    int n_edges = in_sizes[3];

    // workspace layout (aligned)
    char* p = (char*)d_ws;
    auto alloc = [&](size_t bytes, size_t align) -> void* {
        size_t a = (size_t)p; a = (a + align - 1) & ~(align - 1);
        p = (char*)a; void* r = (void*)p; p += bytes; return r;
    };
    float* xsv1 = (float*)alloc((size_t)n_nodes * 128 * 4, 16);
    float* W1s  = (float*)alloc(512 * 4, 16);
    float* W2T  = (float*)alloc(8192 * 4, 16);
    float* mid  = (float*)alloc((size_t)n_nodes * 256 * 4, 16);   // fallback only
    int* counts = (int*)alloc((size_t)n_nodes * 4, 16);
    int* offs   = (int*)alloc(((size_t)n_nodes + 1) * 4, 16);
    int* cursor = (int*)alloc((size_t)n_nodes * 4, 16);
    int* esrc_s = (int*)alloc((size_t)n_edges * 4, 16);
    float4* eattr_s = (float4*)alloc((size_t)n_edges * 16, 16);
    float4* escal_s = (float4*)alloc((size_t)n_edges * 32, 16);
    unsigned short* W2Tb = (unsigned short*)alloc(8192 * 2, 64);
    size_t needed = (size_t)(p - (char*)d_ws);

    prep_kernel<<<32, 256, 0, stream>>>(Wfc1, Wfc2, W1s, W2T, W2Tb);
    node_in_kernel<<<2048, 256, 0, stream>>>(node_input, attr_in, w1s, w1v, xsv1, n_nodes);

    if (ws_size >= needed) {
        hipMemsetAsync(counts, 0, (size_t)n_nodes * sizeof(int), stream);
        count_kernel<<<(n_edges + 255) / 256, 256, 0, stream>>>(edst, counts, n_edges);
        scan_kernel<<<1, 1024, 0, stream>>>(counts, offs, cursor, n_nodes);
        scatter_kernel<<<(n_edges + 255) / 256, 256, 0, stream>>>(
            edst, esrc, eattr, escal, cursor, esrc_s, eattr_s, escal_s, n_edges);
        fused_kernel<<<n_nodes, 256, 0, stream>>>(
            escal_s, W1s, W2Tb, xsv1, esrc_s, eattr_s, offs,
            attr_out, w2s, w2v, out, n_nodes);
    } else {
        hipMemsetAsync(mid, 0, (size_t)n_nodes * 256 * sizeof(float), stream);
        edge_kernel_atomic<<<(n_edges + 255) / 256, 256, 0, stream>>>(
            xsv1, esrc, edst, eattr, escal, W1s, W2T, mid, n_edges);
        node_out_kernel<<<2048, 256, 0, stream>>>(mid, attr_out, w2s, w2v, out, n_nodes);
    }
}